// Round 9
// baseline (31.343 us; speedup 1.0000x reference)
//
#include <hip/hip_runtime.h>

#define EDIM 10
#define CDIM 128
#define DDIM 9
#define BDIM 512
#define NT3 165   // #(a<=b<=c) triples over 9 dims
#define NT2 45    // #(a<=b) pairs
#define NT1 9
#define NT 219
#define SLAB 16
#define NSLAB 14              // ceil(219/16)
#define NCHK 74               // >= worst-case same-species 8-row chunks (<=72)
#define NBLK (NCHK * 2)       // x2 half-channel tiles = 148 blocks

// compile-time (a,b,c) per term; index 9 is the "1.0" slot so pairs/singles
// are uniform triples. Same canonical enumeration order as rounds 2-8.
struct TermCodes { unsigned char a[NT], b[NT], c[NT]; };
constexpr TermCodes make_codes() {
  TermCodes cd{};
  int t = 0;
  for (int i = 0; i < DDIM; ++i)
    for (int j = i; j < DDIM; ++j)
      for (int k = j; k < DDIM; ++k) { cd.a[t] = (unsigned char)i; cd.b[t] = (unsigned char)j; cd.c[t] = (unsigned char)k; ++t; }
  for (int i = 0; i < DDIM; ++i)
    for (int j = i; j < DDIM; ++j) { cd.a[t] = (unsigned char)i; cd.b[t] = (unsigned char)j; cd.c[t] = 9; ++t; }
  for (int i = 0; i < DDIM; ++i) { cd.a[t] = (unsigned char)i; cd.b[t] = 9; cd.c[t] = 9; ++t; }
  return cd;
}
constexpr TermCodes kCD = make_codes();

// ---------------------------------------------------------------------------
// One kernel, one dispatch. Block = 8 same-species rows x 64 channels
// (512 thr, wave = 64 ch, wave id = row slot). Slab-pipelined:
// build slab s+1 (wave-uniform terms, u via uniform float4 loads, w in regs)
// while consuming slab s from LDS (static fully-unrolled term loop).
// ---------------------------------------------------------------------------
__global__ __launch_bounds__(512) void symcon_fused_kernel(
    const float* __restrict__ x, const float* __restrict__ y,
    const float* __restrict__ u1_0e, const float* __restrict__ w1_0e,
    const float* __restrict__ u2_0e, const float* __restrict__ w2_0e,
    const float* __restrict__ u3_0e, const float* __restrict__ w3_0e,
    const float* __restrict__ u1_1o, const float* __restrict__ w1_1o,
    const float* __restrict__ u2_1o, const float* __restrict__ w2_1o,
    const float* __restrict__ u3_1o, const float* __restrict__ w3_1o,
    float* __restrict__ out) {
  __shared__ float4 slab[2][SLAB][64];        // 32 KB double-buffered slice
  __shared__ unsigned int mask[EDIM][16];     // 512-bit row mask per species
  __shared__ int cnt[EDIM], st[EDIM], cb[EDIM + 1];
  __shared__ int slotB[8];

  const int tid = threadIdx.x;
  const int lane = tid & 63;
  const int wv = tid >> 6;                    // wave id = row slot 0..7
  const int chunk = blockIdx.x >> 1;          // 0..NCHK-1
  const int ct = blockIdx.x & 1;              // channel half
  const int c = ct * 64 + lane;

  // ---- deterministic bucketing (bitmask ranks; every block redundantly) ----
  if (tid < EDIM * 16) mask[tid >> 4][tid & 15] = 0u;
  if (tid < 8) slotB[tid] = 0;
  __syncthreads();
  int e_r = 0;
  {
    const float* yr = y + tid * EDIM;         // tid == row (BDIM == 512)
    for (int q = 0; q < EDIM; ++q)
      if (yr[q] > 0.5f) e_r = q;
  }
  atomicOr(&mask[e_r][tid >> 5], 1u << (tid & 31));
  __syncthreads();
  if (tid < EDIM) {
    int s = 0;
    for (int w = 0; w < 16; ++w) s += __popc(mask[tid][w]);
    cnt[tid] = s;
  }
  __syncthreads();
  if (tid == 0) {
    int s = 0, q = 0;
    for (int e = 0; e < EDIM; ++e) {
      st[e] = s; cb[e] = q;
      s += cnt[e]; q += (cnt[e] + 7) >> 3;
    }
    cb[EDIM] = q;
  }
  __syncthreads();
  // my chunk -> (species, window start, row count)
  int eB = -1, start = 0, cntc = 0;
  for (int e = 0; e < EDIM; ++e) {
    if (chunk >= cb[e] && chunk < cb[e + 1]) {
      const int k = chunk - cb[e];
      eB = e; start = st[e] + 8 * k;
      cntc = cnt[e] - 8 * k; if (cntc > 8) cntc = 8;
    }
  }
  if (eB < 0) return;                         // block-uniform: unused chunk
  {
    const int w = tid >> 5, bit = tid & 31;
    int rk = __popc(mask[e_r][w] & ((1u << bit) - 1u));
    for (int ww = 0; ww < w; ++ww) rk += __popc(mask[e_r][ww]);
    const int lp = st[e_r] + rk - start;
    if (e_r == eB && lp >= 0 && lp < 8) slotB[lp] = tid;
  }
  __syncthreads();

  const bool valid = (wv < cntc);
  const int b = slotB[valid ? wv : 0];

  // ---- per-lane x row (xv[9] = 1.0 makes every term a triple) ----
  float xv[10];
  {
    const float* xr = x + ((size_t)b * CDIM + c) * DDIM;
#pragma unroll
    for (int d = 0; d < DDIM; ++d) xv[d] = xr[d];
    xv[9] = 1.0f;
  }

  // ---- per-lane w columns for species eB (28 regs; kills all w traffic) ----
  float w30[8], w31[12], w20[3], w21[4];
#pragma unroll
  for (int k = 0; k < 8; ++k)  w30[k] = w3_0e[(k * EDIM + eB) * CDIM + c];
#pragma unroll
  for (int k = 0; k < 12; ++k) w31[k] = w3_1o[(k * EDIM + eB) * CDIM + c];
#pragma unroll
  for (int k = 0; k < 3; ++k)  w20[k] = w2_0e[(k * EDIM + eB) * CDIM + c];
#pragma unroll
  for (int k = 0; k < 4; ++k)  w21[k] = w2_1o[(k * EDIM + eB) * CDIM + c];
  const float w10 = w1_0e[eB * CDIM + c];
  const float w11 = w1_1o[eB * CDIM + c];

  // ---- build one coefficient term (t is wave-uniform; u loads uniform) ----
  auto build_term = [&](int t, float4* dst) {
    float o0 = 0.f, o1 = 0.f, o2 = 0.f, o3 = 0.f;
    if (t < NT3) {
      int r = t, a = 0, bb = 0;
      for (a = 0; a < DDIM; ++a) { const int n = (DDIM - a) * (DDIM - a + 1) / 2; if (r < n) break; r -= n; }
      for (bb = a; bb < DDIM; ++bb) { const int n = DDIM - bb; if (r < n) break; r -= n; }
      const int cc = bb + r;
      const float mult = (a == bb && bb == cc) ? 1.f : ((a == bb || bb == cc) ? 3.f : 6.f);
      const int ub0 = ((a * DDIM + bb) * DDIM + cc) * 8;   // 32B aligned
      const float4 ua = *reinterpret_cast<const float4*>(u3_0e + ub0);
      const float4 ub = *reinterpret_cast<const float4*>(u3_0e + ub0 + 4);
      o0 = fmaf(ua.x, w30[0], o0); o0 = fmaf(ua.y, w30[1], o0);
      o0 = fmaf(ua.z, w30[2], o0); o0 = fmaf(ua.w, w30[3], o0);
      o0 = fmaf(ub.x, w30[4], o0); o0 = fmaf(ub.y, w30[5], o0);
      o0 = fmaf(ub.z, w30[6], o0); o0 = fmaf(ub.w, w30[7], o0);
      const int ub1 = ((a * DDIM + bb) * DDIM + cc) * 36;  // 144B aligned
      const float4* up = reinterpret_cast<const float4*>(u3_1o + ub1);
      const float4 v0 = up[0], v1 = up[1], v2 = up[2], v3 = up[3], v4 = up[4],
                   v5 = up[5], v6 = up[6], v7 = up[7], v8 = up[8];
      o1 = fmaf(v0.x, w31[0], o1);  o2 = fmaf(v0.y, w31[0], o2);  o3 = fmaf(v0.z, w31[0], o3);
      o1 = fmaf(v0.w, w31[1], o1);  o2 = fmaf(v1.x, w31[1], o2);  o3 = fmaf(v1.y, w31[1], o3);
      o1 = fmaf(v1.z, w31[2], o1);  o2 = fmaf(v1.w, w31[2], o2);  o3 = fmaf(v2.x, w31[2], o3);
      o1 = fmaf(v2.y, w31[3], o1);  o2 = fmaf(v2.z, w31[3], o2);  o3 = fmaf(v2.w, w31[3], o3);
      o1 = fmaf(v3.x, w31[4], o1);  o2 = fmaf(v3.y, w31[4], o2);  o3 = fmaf(v3.z, w31[4], o3);
      o1 = fmaf(v3.w, w31[5], o1);  o2 = fmaf(v4.x, w31[5], o2);  o3 = fmaf(v4.y, w31[5], o3);
      o1 = fmaf(v4.z, w31[6], o1);  o2 = fmaf(v4.w, w31[6], o2);  o3 = fmaf(v5.x, w31[6], o3);
      o1 = fmaf(v5.y, w31[7], o1);  o2 = fmaf(v5.z, w31[7], o2);  o3 = fmaf(v5.w, w31[7], o3);
      o1 = fmaf(v6.x, w31[8], o1);  o2 = fmaf(v6.y, w31[8], o2);  o3 = fmaf(v6.z, w31[8], o3);
      o1 = fmaf(v6.w, w31[9], o1);  o2 = fmaf(v7.x, w31[9], o2);  o3 = fmaf(v7.y, w31[9], o3);
      o1 = fmaf(v7.z, w31[10], o1); o2 = fmaf(v7.w, w31[10], o2); o3 = fmaf(v8.x, w31[10], o3);
      o1 = fmaf(v8.y, w31[11], o1); o2 = fmaf(v8.z, w31[11], o2); o3 = fmaf(v8.w, w31[11], o3);
      o0 *= mult; o1 *= mult; o2 *= mult; o3 *= mult;
    } else if (t < NT3 + NT2) {
      int r = t - NT3, a = 0;
      for (a = 0; a < DDIM; ++a) { const int n = DDIM - a; if (r < n) break; r -= n; }
      const int bb = a + r;
      const float mult = (a == bb) ? 1.f : 2.f;
      const int p = a * DDIM + bb;
      const int ub0 = p * 3;                               // 12B stride: scalar loads
      o0 = fmaf(u2_0e[ub0 + 0], w20[0], o0);
      o0 = fmaf(u2_0e[ub0 + 1], w20[1], o0);
      o0 = fmaf(u2_0e[ub0 + 2], w20[2], o0);
      const int ub1 = p * 12;                              // 48B aligned
      const float4* up = reinterpret_cast<const float4*>(u2_1o + ub1);
      const float4 v0 = up[0], v1 = up[1], v2 = up[2];
      o1 = fmaf(v0.x, w21[0], o1); o2 = fmaf(v0.y, w21[0], o2); o3 = fmaf(v0.z, w21[0], o3);
      o1 = fmaf(v0.w, w21[1], o1); o2 = fmaf(v1.x, w21[1], o2); o3 = fmaf(v1.y, w21[1], o3);
      o1 = fmaf(v1.z, w21[2], o1); o2 = fmaf(v1.w, w21[2], o2); o3 = fmaf(v2.x, w21[2], o3);
      o1 = fmaf(v2.y, w21[3], o1); o2 = fmaf(v2.z, w21[3], o2); o3 = fmaf(v2.w, w21[3], o3);
      o0 *= mult; o1 *= mult; o2 *= mult; o3 *= mult;
    } else {
      const int j = t - NT3 - NT2;
      o0 = u1_0e[j] * w10;
      o1 = u1_1o[j * 3 + 0] * w11;
      o2 = u1_1o[j * 3 + 1] * w11;
      o3 = u1_1o[j * 3 + 2] * w11;
    }
    *dst = make_float4(o0, o1, o2, o3);
  };

  auto build2 = [&](int s, int buf) {      // wave builds its 2 terms of slab s
    const int t = s * SLAB + wv * 2;
    if (t < NT) build_term(t, &slab[buf][wv * 2 + 0][lane]);
    if (t + 1 < NT) build_term(t + 1, &slab[buf][wv * 2 + 1][lane]);
  };

  float a0 = 0.f, a1 = 0.f, a2 = 0.f, a3 = 0.f;
  build2(0, 0);
  __syncthreads();
#pragma unroll
  for (int s = 0; s < NSLAB; ++s) {
    if (s + 1 < NSLAB) build2(s + 1, (s + 1) & 1);   // overlap with consume
#pragma unroll
    for (int tl = 0; tl < SLAB; ++tl) {
      const int t = s * SLAB + tl;                    // compile-time constant
      if (t < NT) {
        const float m = xv[kCD.a[t]] * xv[kCD.b[t]] * xv[kCD.c[t]];  // static idx
        const float4 tv = slab[s & 1][tl][lane];      // contiguous ds_read_b128
        a0 = fmaf(tv.x, m, a0);
        a1 = fmaf(tv.y, m, a1);
        a2 = fmaf(tv.z, m, a2);
        a3 = fmaf(tv.w, m, a3);
      }
    }
    __syncthreads();
  }

  if (valid) {
    float4* o = reinterpret_cast<float4*>(out) + ((size_t)b * CDIM + c);
    *o = make_float4(a0, a1, a2, a3);
  }
}

extern "C" void kernel_launch(void* const* d_in, const int* in_sizes, int n_in,
                              void* d_out, int out_size, void* d_ws, size_t ws_size,
                              hipStream_t stream) {
  const float* x     = (const float*)d_in[0];
  const float* y     = (const float*)d_in[1];
  const float* u1_0e = (const float*)d_in[2];
  const float* w1_0e = (const float*)d_in[3];
  const float* u2_0e = (const float*)d_in[4];
  const float* w2_0e = (const float*)d_in[5];
  const float* u3_0e = (const float*)d_in[6];
  const float* w3_0e = (const float*)d_in[7];
  const float* u1_1o = (const float*)d_in[8];
  const float* w1_1o = (const float*)d_in[9];
  const float* u2_1o = (const float*)d_in[10];
  const float* w2_1o = (const float*)d_in[11];
  const float* u3_1o = (const float*)d_in[12];
  const float* w3_1o = (const float*)d_in[13];

  hipLaunchKernelGGL(symcon_fused_kernel, dim3(NBLK), dim3(512), 0, stream,
                     x, y, u1_0e, w1_0e, u2_0e, w2_0e, u3_0e, w3_0e,
                     u1_1o, w1_1o, u2_1o, w2_1o, u3_1o, w3_1o,
                     (float*)d_out);
}

// Round 10
// 17.812 us; speedup vs baseline: 1.7596x; 1.7596x over previous
//
#include <hip/hip_runtime.h>

#define EDIM 10
#define CDIM 128
#define DDIM 9
#define BDIM 512
#define NT3 165   // #(a<=b<=c) triples over 9 dims
#define NT2 45    // #(a<=b) pairs
#define NT1 9
#define NT 219
#define NCH 26    // worst case sum_e ceil(n_e/32) = 512/32 + 10 = 26

// ws layout:
//   T:        [EDIM][NT][CDIM][4] float  (~4.49 MB)  (t-major, c inner: coalesced)
//   sortedB:  int[BDIM]
//   chunkE/S/C: int[NCH] each
#define TABLE_FLOATS ((size_t)EDIM * NT * CDIM * 4)

// ---------------------------------------------------------------------------
// Kernel A (round-7 exact): blocks 0..EDIM*NT-1 build the coefficient table
// (one (e,t) per 128-thread block: u loads wave-uniform, w loads + T stores
// coalesced). Block EDIM*NT buckets rows by species and emits same-species
// chunks of <=32 rows — fully parallel, no serial tail.
// ---------------------------------------------------------------------------
__global__ __launch_bounds__(CDIM) void table_bucket_kernel(
    const float* __restrict__ u1_0e, const float* __restrict__ w1_0e,
    const float* __restrict__ u2_0e, const float* __restrict__ w2_0e,
    const float* __restrict__ u3_0e, const float* __restrict__ w3_0e,
    const float* __restrict__ u1_1o, const float* __restrict__ w1_1o,
    const float* __restrict__ u2_1o, const float* __restrict__ w2_1o,
    const float* __restrict__ u3_1o, const float* __restrict__ w3_1o,
    const float* __restrict__ y,
    float* __restrict__ T, int* __restrict__ sortedB,
    int* __restrict__ chunkE, int* __restrict__ chunkS, int* __restrict__ chunkC) {
  if (blockIdx.x == EDIM * NT) {
    // ---- species bucketing: 128 threads x 4 rows each ----
    __shared__ int cnt[EDIM];
    __shared__ int st[EDIM];
    __shared__ int rk[EDIM];
    const int tid = threadIdx.x;
    if (tid < EDIM) { cnt[tid] = 0; rk[tid] = 0; }
    if (tid >= 64 && tid < 64 + NCH) chunkC[tid - 64] = 0;  // pre-zero chunks
    __syncthreads();
    int mye[4];
#pragma unroll
    for (int k = 0; k < 4; ++k) {
      const int b = tid + 128 * k;
      int e = 0;
      for (int q = 0; q < EDIM; ++q)
        if (y[b * EDIM + q] > 0.5f) e = q;
      mye[k] = e;
      atomicAdd(&cnt[e], 1);
    }
    __syncthreads();
    if (tid < EDIM) {
      int s = 0;
      for (int j = 0; j < tid; ++j) s += cnt[j];
      st[tid] = s;
    }
    __syncthreads();
    if (tid < EDIM) {
      // chunk metadata for my species (order-independent, parallel)
      int base = 0;
      for (int j = 0; j < tid; ++j) base += (cnt[j] + 31) >> 5;
      const int n = cnt[tid];
      const int nch = (n + 31) >> 5;
      for (int k = 0; k < nch; ++k) {
        chunkE[base + k] = tid;
        chunkS[base + k] = st[tid] + 32 * k;
        chunkC[base + k] = (n - 32 * k < 32) ? (n - 32 * k) : 32;
      }
    }
#pragma unroll
    for (int k = 0; k < 4; ++k) {
      const int b = tid + 128 * k;
      const int e = mye[k];
      const int r = atomicAdd(&rk[e], 1);
      sortedB[st[e] + r] = b;   // order within species irrelevant
    }
    return;
  }

  // ---- table build (round-2 verified layout/order) ----
  const int c = threadIdx.x;           // channel
  const int blk = blockIdx.x;          // e * NT + t
  const int e = blk / NT;
  const int t = blk - e * NT;

  float o0 = 0.f, o1 = 0.f, o2 = 0.f, o3 = 0.f;

  if (t < NT3) {
    int r = t, a = 0, b = 0;
    for (a = 0; a < DDIM; ++a) {
      int n = (DDIM - a) * (DDIM - a + 1) / 2;
      if (r < n) break;
      r -= n;
    }
    for (b = a; b < DDIM; ++b) {
      int n = DDIM - b;
      if (r < n) break;
      r -= n;
    }
    const int cc = b + r;
    const float mult = (a == b && b == cc) ? 1.f : ((a == b || b == cc) ? 3.f : 6.f);

    const int ub0 = ((a * DDIM + b) * DDIM + cc) * 8;       // u3_0e: (9,9,9,8,1)
    for (int k = 0; k < 8; ++k)
      o0 += u3_0e[ub0 + k] * w3_0e[(k * EDIM + e) * CDIM + c];

    const int ub1 = ((a * DDIM + b) * DDIM + cc) * 36;      // u3_1o: (9,9,9,12,3)
    for (int k = 0; k < 12; ++k) {
      const float wv = w3_1o[(k * EDIM + e) * CDIM + c];
      o1 += u3_1o[ub1 + k * 3 + 0] * wv;
      o2 += u3_1o[ub1 + k * 3 + 1] * wv;
      o3 += u3_1o[ub1 + k * 3 + 2] * wv;
    }
    o0 *= mult; o1 *= mult; o2 *= mult; o3 *= mult;
  } else if (t < NT3 + NT2) {
    int r = t - NT3, a = 0;
    for (a = 0; a < DDIM; ++a) {
      int n = DDIM - a;
      if (r < n) break;
      r -= n;
    }
    const int b = a + r;
    const float mult = (a == b) ? 1.f : 2.f;

    const int ub0 = (a * DDIM + b) * 3;                     // u2_0e: (9,9,3,1)
    for (int k = 0; k < 3; ++k)
      o0 += u2_0e[ub0 + k] * w2_0e[(k * EDIM + e) * CDIM + c];

    const int ub1 = (a * DDIM + b) * 12;                    // u2_1o: (9,9,4,3)
    for (int k = 0; k < 4; ++k) {
      const float wv = w2_1o[(k * EDIM + e) * CDIM + c];
      o1 += u2_1o[ub1 + k * 3 + 0] * wv;
      o2 += u2_1o[ub1 + k * 3 + 1] * wv;
      o3 += u2_1o[ub1 + k * 3 + 2] * wv;
    }
    o0 *= mult; o1 *= mult; o2 *= mult; o3 *= mult;
  } else {
    const int j = t - NT3 - NT2;
    o0 = u1_0e[j] * w1_0e[e * CDIM + c];                    // u1_0e: (9,1,1)
    const float wv = w1_1o[e * CDIM + c];
    o1 = u1_1o[j * 3 + 0] * wv;                             // u1_1o: (9,1,3)
    o2 = u1_1o[j * 3 + 1] * wv;
    o3 = u1_1o[j * 3 + 2] * wv;
  }

  float4* dst = reinterpret_cast<float4*>(T) + (size_t)(e * NT + t) * CDIM + c;
  *dst = make_float4(o0, o1, o2, o3);
}

// ---------------------------------------------------------------------------
// Kernel B (round-7 exact): grid = NCH chunks x 16 channel-tiles. Block (256
// thr) = 32 same-species rows x 8 channels. Stage the 219x8 slice (28 KB)
// into LDS once (coalesced), then 4 waves run the 219-term polynomial from
// LDS (8 unique 16 B addrs / read -> conflict-free, slot-broadcast).
// ---------------------------------------------------------------------------
__global__ __launch_bounds__(256) void symcon_main_kernel(
    const float* __restrict__ x, const float* __restrict__ T,
    const int* __restrict__ sortedB, const int* __restrict__ chunkE,
    const int* __restrict__ chunkS, const int* __restrict__ chunkC,
    float* __restrict__ out) {
  __shared__ float4 slice[NT * 8];   // 28 KB  [t][cl]
  __shared__ float xs[32 * 72];      // 9.2 KB [slot][cl*9+d]

  const int bid = blockIdx.x;
  const int chunk = bid >> 4;        // 0..NCH-1
  const int ct = bid & 15;           // channel tile (8 ch)
  const int cntc = chunkC[chunk];
  if (cntc == 0) return;
  const int e = chunkE[chunk];
  const int start = chunkS[chunk];

  const int tid = threadIdx.x;
  const int cl = tid & 7;
  const int slot = tid >> 3;         // 0..31
  const int c = ct * 8 + cl;
  const bool valid = (slot < cntc);
  const int b = sortedB[start + (valid ? slot : cntc - 1)];

  // ---- stage coefficient slice: 1752 float4, coalesced 128B groups ----
  {
    const float4* Tg = reinterpret_cast<const float4*>(T) +
                       (size_t)e * NT * CDIM + ct * 8;
#pragma unroll
    for (int k = 0; k < 7; ++k) {
      const int idx = tid + (k << 8);
      if (idx < NT * 8) {
        const int t = idx >> 3;
        const int j = idx & 7;
        slice[idx] = Tg[(size_t)t * CDIM + j];
      }
    }
  }

  // ---- stage x: slot's 8-channel strip, 18 aligned float4 ----
  {
    const float4* gb = reinterpret_cast<const float4*>(
        x + ((size_t)b * CDIM + ct * 8) * DDIM);  // byte off b*4608+ct*288 (16B aligned)
    float4* xf4 = reinterpret_cast<float4*>(&xs[0]);
    xf4[slot * 18 + cl] = gb[cl];
    xf4[slot * 18 + cl + 8] = gb[cl + 8];
    if (cl < 2) xf4[slot * 18 + cl + 16] = gb[cl + 16];
  }
  __syncthreads();

  float xv[DDIM];
#pragma unroll
  for (int d = 0; d < DDIM; ++d)
    xv[d] = xs[slot * 72 + cl * 9 + d];  // 2 lanes/bank -> free

  float a0 = 0.f, a1 = 0.f, a2 = 0.f, a3 = 0.f;
  int t = 0;

  // order 3: a<=b2<=c3 (same enumeration order as the table build)
#pragma unroll
  for (int a = 0; a < DDIM; ++a) {
#pragma unroll
    for (int b2 = a; b2 < DDIM; ++b2) {
      const float xab = xv[a] * xv[b2];
#pragma unroll
      for (int c3 = b2; c3 < DDIM; ++c3) {
        const float m = xab * xv[c3];
        const float4 tv = slice[t * 8 + cl];
        a0 = fmaf(tv.x, m, a0);
        a1 = fmaf(tv.y, m, a1);
        a2 = fmaf(tv.z, m, a2);
        a3 = fmaf(tv.w, m, a3);
        ++t;
      }
    }
  }
  // order 2
#pragma unroll
  for (int a = 0; a < DDIM; ++a) {
#pragma unroll
    for (int b2 = a; b2 < DDIM; ++b2) {
      const float m = xv[a] * xv[b2];
      const float4 tv = slice[t * 8 + cl];
      a0 = fmaf(tv.x, m, a0);
      a1 = fmaf(tv.y, m, a1);
      a2 = fmaf(tv.z, m, a2);
      a3 = fmaf(tv.w, m, a3);
      ++t;
    }
  }
  // order 1
#pragma unroll
  for (int j = 0; j < DDIM; ++j) {
    const float m = xv[j];
    const float4 tv = slice[t * 8 + cl];
    a0 = fmaf(tv.x, m, a0);
    a1 = fmaf(tv.y, m, a1);
    a2 = fmaf(tv.z, m, a2);
    a3 = fmaf(tv.w, m, a3);
    ++t;
  }

  if (valid) {
    float4* o = reinterpret_cast<float4*>(out) + ((size_t)b * CDIM + c);
    *o = make_float4(a0, a1, a2, a3);
  }
}

extern "C" void kernel_launch(void* const* d_in, const int* in_sizes, int n_in,
                              void* d_out, int out_size, void* d_ws, size_t ws_size,
                              hipStream_t stream) {
  const float* x     = (const float*)d_in[0];
  const float* y     = (const float*)d_in[1];
  const float* u1_0e = (const float*)d_in[2];
  const float* w1_0e = (const float*)d_in[3];
  const float* u2_0e = (const float*)d_in[4];
  const float* w2_0e = (const float*)d_in[5];
  const float* u3_0e = (const float*)d_in[6];
  const float* w3_0e = (const float*)d_in[7];
  const float* u1_1o = (const float*)d_in[8];
  const float* w1_1o = (const float*)d_in[9];
  const float* u2_1o = (const float*)d_in[10];
  const float* w2_1o = (const float*)d_in[11];
  const float* u3_1o = (const float*)d_in[12];
  const float* w3_1o = (const float*)d_in[13];

  float* T = (float*)d_ws;
  int* sortedB = (int*)((float*)d_ws + TABLE_FLOATS);
  int* chunkE = sortedB + BDIM;
  int* chunkS = chunkE + NCH;
  int* chunkC = chunkS + NCH;
  float* out = (float*)d_out;

  const size_t need = TABLE_FLOATS * sizeof(float) +
                      (BDIM + 3 * NCH) * sizeof(int);
  if (ws_size < need) return;

  hipLaunchKernelGGL(table_bucket_kernel, dim3(EDIM * NT + 1), dim3(CDIM), 0, stream,
                     u1_0e, w1_0e, u2_0e, w2_0e, u3_0e, w3_0e,
                     u1_1o, w1_1o, u2_1o, w2_1o, u3_1o, w3_1o,
                     y, T, sortedB, chunkE, chunkS, chunkC);

  hipLaunchKernelGGL(symcon_main_kernel, dim3(NCH * 16), dim3(256), 0, stream,
                     x, T, sortedB, chunkE, chunkS, chunkC, out);
}